// Round 5
// baseline (600.141 us; speedup 1.0000x reference)
//
#include <hip/hip_runtime.h>
#include <hip/hip_bf16.h>

// Transformer block: B=32 T=512 C=512 H=8 D=64
// Round 5: GEMM K-loop restructured -- NO LDS, NO barriers. MFMA fragments
// loaded directly from global (K-major layouts make frag = dwordx4), manual
// register double-buffer so loads run >=1 k-step ahead (AITER-style
// MFMA<->load interleave with fine vmcnt instead of the vmcnt(0)+barrier
// drain that capped rounds 3-4 at ~13% MfmaUtil). Epilogues unchanged.

#define B_  32
#define T_  512
#define C_  512
#define H_  8
#define D_  64
#define BT  (B_*T_)      // 16384 rows
#define CF  2048         // 4*C

typedef __hip_bfloat16 bf16;
typedef __attribute__((ext_vector_type(8))) short bf16x8;   // 8 bf16 (4 VGPRs)
typedef __attribute__((ext_vector_type(4))) float f32x4;
typedef __attribute__((ext_vector_type(4))) short short4v;

__device__ __forceinline__ float bf2f(bf16 x) { return __bfloat162float(x); }
__device__ __forceinline__ bf16  f2bf(float x){ return __float2bfloat16(x); }
__device__ __forceinline__ short f2bf_bits(float f){
    bf16 h = __float2bfloat16(f);
    return *reinterpret_cast<short*>(&h);
}
__device__ __forceinline__ float bfbits2f(short s){
    unsigned u = ((unsigned)(unsigned short)s) << 16;
    return __uint_as_float(u);
}

// ---------------- All weight transposes in one launch ------------------------
__global__ __launch_bounds__(256) void transpose_all(const float* __restrict__ wq,
                                                     const float* __restrict__ wk,
                                                     const float* __restrict__ wv,
                                                     const float* __restrict__ wproj,
                                                     const float* __restrict__ w1,
                                                     const float* __restrict__ w2,
                                                     bf16* __restrict__ wt)
{
    const int t = blockIdx.x;
    const float* src; int K, Nn, k0, n0; size_t dstoff;
    if (t < 192) {
        const int which = t / 64, w = t % 64, hh = w >> 3, kt = w & 7;
        src = (which == 0 ? wq : which == 1 ? wk : wv) + (size_t)hh * 512 * 64;
        K = 512; Nn = 64; k0 = kt * 64; n0 = 0;
        dstoff = (size_t)(which * 512 + hh * 64) * 512;
    } else if (t < 256) {
        const int i = t - 192;
        src = wproj; K = 512; Nn = 512; n0 = (i & 7) * 64; k0 = (i >> 3) * 64;
        dstoff = (size_t)1536 * 512;
    } else if (t < 512) {
        const int i = t - 256;
        src = w1; K = 512; Nn = 2048; n0 = (i & 31) * 64; k0 = (i >> 5) * 64;
        dstoff = (size_t)2048 * 512;
    } else {
        const int i = t - 512;
        src = w2; K = 2048; Nn = 512; n0 = (i & 7) * 64; k0 = (i >> 3) * 64;
        dstoff = (size_t)2048 * 512 + (size_t)2048 * 512;
    }

    __shared__ float tl[64][65];
    const int tid = threadIdx.x;
    #pragma unroll
    for (int j = 0; j < 16; ++j) {
        const int e = j * 256 + tid, r = e >> 6, c = e & 63;
        tl[r][c] = src[(size_t)(k0 + r) * Nn + n0 + c];
    }
    __syncthreads();
    #pragma unroll
    for (int j = 0; j < 16; ++j) {
        const int e = j * 256 + tid, n = e >> 6, kk = e & 63;
        wt[dstoff + (size_t)(n0 + n) * K + k0 + kk] = f2bf(tl[kk][n]);
    }
}

// ---------------- LayerNorm: one block per row (C=512), 256 threads ----------
__global__ __launch_bounds__(256) void ln_kernel(const float* __restrict__ x,
                                                 const float* __restrict__ g,
                                                 const float* __restrict__ b,
                                                 bf16* __restrict__ out)
{
    const int row = blockIdx.x;
    const int tid = threadIdx.x;
    const float* xr = x + (size_t)row * C_;
    float v0 = xr[tid], v1 = xr[tid + 256];

    __shared__ float red[4];

    float s = v0 + v1;
    #pragma unroll
    for (int off = 32; off > 0; off >>= 1) s += __shfl_down(s, off, 64);
    if ((tid & 63) == 0) red[tid >> 6] = s;
    __syncthreads();
    const float mean = (red[0] + red[1] + red[2] + red[3]) * (1.0f / C_);
    __syncthreads();

    float d0 = v0 - mean, d1 = v1 - mean;
    float vs = d0 * d0 + d1 * d1;
    #pragma unroll
    for (int off = 32; off > 0; off >>= 1) vs += __shfl_down(vs, off, 64);
    if ((tid & 63) == 0) red[tid >> 6] = vs;
    __syncthreads();
    const float var  = (red[0] + red[1] + red[2] + red[3]) * (1.0f / C_);
    const float rstd = rsqrtf(var + 1e-5f);

    bf16* orow = out + (size_t)row * C_;
    orow[tid]       = f2bf(d0 * rstd * g[tid]       + b[tid]);
    orow[tid + 256] = f2bf(d1 * rstd * g[tid + 256] + b[tid + 256]);
}

// ---------------- MFMA GEMM: C[M,N] = A[M,K](bf16) * Bt[N,K](bf16)^T ---------
// 128x128 tile, 256 threads = 4 waves (2x2 of 64x64). No LDS, no barriers:
// fragments loaded straight from global (K-major => frag = dwordx4/lane),
// register double-buffered one k-step (32) ahead.
// Default: C^T accumulation (mfma(b,a)) -> packed epilogue stores.
// QKV: N=1536, q/k -> (B,H,T,D) dd-packed; v third -> (B,H,D,T) t-packed.
template<bool QKV, bool RELU, bool OUT_BF16>
__global__ __launch_bounds__(256) void mfma_gemm(const bf16* __restrict__ A,
                                                 const bf16* __restrict__ Bt,
                                                 const float* __restrict__ bias,
                                                 const float* __restrict__ res,
                                                 void* __restrict__ outp,
                                                 int N, int K)
{
    const int tid  = threadIdx.x;
    const int wave = tid >> 6, lane = tid & 63;
    const int l16  = lane & 15, quad = lane >> 4;
    const int wm   = wave >> 1, wn = wave & 1;
    const int tm   = blockIdx.y * 128, tn = blockIdx.x * 128;
    const bool vblk = QKV && (tn >= 1024);     // v third of the merged QKV GEMM

    // per-lane fragment base pointers (fragment f at +f*16*K, k-step at +k0)
    const bf16* aB = A  + (size_t)(tm + wm * 64 + l16) * K + quad * 8;
    const bf16* bB = Bt + (size_t)(tn + wn * 64 + l16) * K + quad * 8;

    f32x4 acc[4][4];
    #pragma unroll
    for (int i = 0; i < 4; ++i)
        #pragma unroll
        for (int j = 0; j < 4; ++j) acc[i][j] = (f32x4){0.f, 0.f, 0.f, 0.f};

    auto do_mfma = [&](bf16x8 (&af)[4], bf16x8 (&bfr)[4]) {
        if (vblk) {
            #pragma unroll
            for (int mf = 0; mf < 4; ++mf)
                #pragma unroll
                for (int nf = 0; nf < 4; ++nf)
                    acc[mf][nf] = __builtin_amdgcn_mfma_f32_16x16x32_bf16(af[mf], bfr[nf], acc[mf][nf], 0, 0, 0);
        } else {
            #pragma unroll
            for (int mf = 0; mf < 4; ++mf)
                #pragma unroll
                for (int nf = 0; nf < 4; ++nf)
                    acc[mf][nf] = __builtin_amdgcn_mfma_f32_16x16x32_bf16(bfr[nf], af[mf], acc[mf][nf], 0, 0, 0);
        }
    };

    bf16x8 a0[4], b0[4], a1[4], b1[4];
    #pragma unroll
    for (int f = 0; f < 4; ++f) {
        a0[f] = *(const bf16x8*)(aB + (size_t)f * 16 * K);
        b0[f] = *(const bf16x8*)(bB + (size_t)f * 16 * K);
    }

    for (int k0 = 0; k0 < K; k0 += 64) {
        #pragma unroll
        for (int f = 0; f < 4; ++f) {
            a1[f] = *(const bf16x8*)(aB + (size_t)f * 16 * K + k0 + 32);
            b1[f] = *(const bf16x8*)(bB + (size_t)f * 16 * K + k0 + 32);
        }
        do_mfma(a0, b0);
        if (k0 + 64 < K) {
            #pragma unroll
            for (int f = 0; f < 4; ++f) {
                a0[f] = *(const bf16x8*)(aB + (size_t)f * 16 * K + k0 + 64);
                b0[f] = *(const bf16x8*)(bB + (size_t)f * 16 * K + k0 + 64);
            }
        }
        do_mfma(a1, b1);
    }

    if (QKV) {
        bf16* qkv = (bf16*)outp;                 // q base; k at +8M elems, v at +16M
        if (!vblk) {
            const int which = tn >> 9;           // 0=q, 1=k
            bf16* dst = qkv + (size_t)which * (8u << 20);
            #pragma unroll
            for (int mf = 0; mf < 4; ++mf) {
                const int m = tm + wm * 64 + mf * 16 + l16;   // token (C^T: col=m)
                const int bb = m >> 9, t = m & 511;
                #pragma unroll
                for (int nf = 0; nf < 4; ++nf) {
                    const int nb = tn + wn * 64 + nf * 16 + quad * 4;
                    const int hh = (nb >> 6) & 7, dd = nb & 63;
                    short4v pk;
                    #pragma unroll
                    for (int r = 0; r < 4; ++r) pk[r] = f2bf_bits(acc[mf][nf][r]);
                    *(short4v*)&dst[((size_t)(bb * 8 + hh) * 512 + t) * 64 + dd] = pk;
                }
            }
        } else {
            bf16* dst = qkv + (size_t)2 * (8u << 20);
            #pragma unroll
            for (int mf = 0; mf < 4; ++mf) {
                const int mb = tm + wm * 64 + mf * 16 + quad * 4;   // token base
                const int bb = mb >> 9, t = mb & 511;
                #pragma unroll
                for (int nf = 0; nf < 4; ++nf) {
                    const int n = tn + wn * 64 + nf * 16 + l16;
                    const int hh = (n >> 6) & 7, dd = n & 63;
                    short4v pk;
                    #pragma unroll
                    for (int r = 0; r < 4; ++r) pk[r] = f2bf_bits(acc[mf][nf][r]);
                    *(short4v*)&dst[((size_t)(bb * 8 + hh) * 64 + dd) * 512 + t] = pk;
                }
            }
        }
    } else {
        #pragma unroll
        for (int mf = 0; mf < 4; ++mf) {
            const int m = tm + wm * 64 + mf * 16 + l16;             // C^T: col=m
            #pragma unroll
            for (int nf = 0; nf < 4; ++nf) {
                const int nb = tn + wn * 64 + nf * 16 + quad * 4;   // 4 consecutive n
                f32x4 a = acc[mf][nf];
                if (bias) a += *(const f32x4*)&bias[nb];
                if (RELU) {
                    #pragma unroll
                    for (int r = 0; r < 4; ++r) a[r] = fmaxf(a[r], 0.0f);
                }
                if (res)  a += *(const f32x4*)&res[(size_t)m * N + nb];
                if (OUT_BF16) {
                    short4v pk;
                    #pragma unroll
                    for (int r = 0; r < 4; ++r) pk[r] = f2bf_bits(a[r]);
                    *(short4v*)&((bf16*)outp)[(size_t)m * N + nb] = pk;
                } else {
                    *(f32x4*)&((float*)outp)[(size_t)m * N + nb] = a;
                }
            }
        }
    }
}

// ---------------- Flash attention: MFMA 16x16x32 bf16 (unchanged) ------------
__global__ __launch_bounds__(256) void attn_kernel(const bf16* __restrict__ q,
                                                   const bf16* __restrict__ kM,
                                                   const bf16* __restrict__ vT,
                                                   bf16* __restrict__ o)
{
    __shared__ __align__(16) bf16 Ks[64][72];
    __shared__ __align__(16) bf16 Vt[64][72];
    __shared__ __align__(16) bf16 Pw[4][16][72];

    const int qt   = gridDim.x - 1 - blockIdx.x;
    const int bh   = blockIdx.y;
    const int tid  = threadIdx.x;
    const int wave = tid >> 6, lane = tid & 63;
    const int l16  = lane & 15, quad = lane >> 4;
    const int qw   = qt * 64 + wave * 16;

    const float scale = 0.04419417382415922f;  // C^-0.5 (reference uses n_embd)
    bf16x8 qa[2];
    #pragma unroll
    for (int c = 0; c < 2; ++c) {
        const bf16* qp = q + ((size_t)bh * T_ + qw + l16) * 64 + c * 32 + quad * 8;
        bf16x8 t = *(const bf16x8*)qp;
        #pragma unroll
        for (int j = 0; j < 8; ++j) t[j] = f2bf_bits(bfbits2f(t[j]) * scale);
        qa[c] = t;
    }

    float m_i[4], l_i[4];
    f32x4 Of[4];
    #pragma unroll
    for (int r = 0; r < 4; ++r) { m_i[r] = -1e30f; l_i[r] = 0.0f; }
    #pragma unroll
    for (int f = 0; f < 4; ++f) Of[f] = (f32x4){0.f, 0.f, 0.f, 0.f};

    for (int kt = 0; kt <= qt; ++kt) {
        const int k0 = kt * 64;
        __syncthreads();
        #pragma unroll
        for (int c2 = 0; c2 < 2; ++c2) {
            const int ch = tid + c2 * 256;
            const int row = ch >> 3, e8 = (ch & 7) * 8;
            *(uint4*)&Ks[row][e8] = *(const uint4*)(kM + ((size_t)bh * T_ + k0 + row) * 64 + e8);
            *(uint4*)&Vt[row][e8] = *(const uint4*)(vT + ((size_t)bh * 64 + row) * T_ + k0 + e8);
        }
        __syncthreads();

        f32x4 Sf[4];
        #pragma unroll
        for (int kf = 0; kf < 4; ++kf) {
            bf16x8 b0 = *(const bf16x8*)&Ks[kf * 16 + l16][quad * 8];
            bf16x8 b1 = *(const bf16x8*)&Ks[kf * 16 + l16][32 + quad * 8];
            f32x4 z = (f32x4){0.f, 0.f, 0.f, 0.f};
            z = __builtin_amdgcn_mfma_f32_16x16x32_bf16(qa[0], b0, z, 0, 0, 0);
            z = __builtin_amdgcn_mfma_f32_16x16x32_bf16(qa[1], b1, z, 0, 0, 0);
            Sf[kf] = z;
        }

        if (kt == qt) {
            #pragma unroll
            for (int kf = 0; kf < 4; ++kf)
                #pragma unroll
                for (int r = 0; r < 4; ++r)
                    if (k0 + kf * 16 + l16 > qw + quad * 4 + r) Sf[kf][r] = -1e30f;
        }

        float mnew[4], alpha[4];
        #pragma unroll
        for (int r = 0; r < 4; ++r) {
            float v = fmaxf(fmaxf(Sf[0][r], Sf[1][r]), fmaxf(Sf[2][r], Sf[3][r]));
            v = fmaxf(v, __shfl_xor(v, 1, 64));
            v = fmaxf(v, __shfl_xor(v, 2, 64));
            v = fmaxf(v, __shfl_xor(v, 4, 64));
            v = fmaxf(v, __shfl_xor(v, 8, 64));
            mnew[r]  = fmaxf(m_i[r], v);
            alpha[r] = __expf(m_i[r] - mnew[r]);
            m_i[r]   = mnew[r];
        }

        float rs[4] = {0.f, 0.f, 0.f, 0.f};
        #pragma unroll
        for (int kf = 0; kf < 4; ++kf) {
            #pragma unroll
            for (int r = 0; r < 4; ++r) {
                float p = __expf(Sf[kf][r] - mnew[r]);
                rs[r] += p;
                Pw[wave][quad * 4 + r][kf * 16 + l16] = f2bf(p);
            }
        }
        #pragma unroll
        for (int r = 0; r < 4; ++r) {
            rs[r] += __shfl_xor(rs[r], 1, 64);
            rs[r] += __shfl_xor(rs[r], 2, 64);
            rs[r] += __shfl_xor(rs[r], 4, 64);
            rs[r] += __shfl_xor(rs[r], 8, 64);
            l_i[r] = l_i[r] * alpha[r] + rs[r];
        }
        #pragma unroll
        for (int f = 0; f < 4; ++f)
            #pragma unroll
            for (int r = 0; r < 4; ++r)
                Of[f][r] *= alpha[r];

        bf16x8 pa0 = *(const bf16x8*)&Pw[wave][l16][quad * 8];
        bf16x8 pa1 = *(const bf16x8*)&Pw[wave][l16][32 + quad * 8];
        #pragma unroll
        for (int f = 0; f < 4; ++f) {
            bf16x8 vb0 = *(const bf16x8*)&Vt[f * 16 + l16][quad * 8];
            bf16x8 vb1 = *(const bf16x8*)&Vt[f * 16 + l16][32 + quad * 8];
            Of[f] = __builtin_amdgcn_mfma_f32_16x16x32_bf16(pa0, vb0, Of[f], 0, 0, 0);
            Of[f] = __builtin_amdgcn_mfma_f32_16x16x32_bf16(pa1, vb1, Of[f], 0, 0, 0);
        }
    }

    const int b = bh >> 3, hh = bh & 7;
    #pragma unroll
    for (int r = 0; r < 4; ++r) {
        const float inv = 1.0f / l_i[r];
        const int t = qw + quad * 4 + r;
        #pragma unroll
        for (int f = 0; f < 4; ++f)
            o[((size_t)b * T_ + t) * C_ + hh * 64 + f * 16 + l16] = f2bf(Of[f][r] * inv);
    }
}

// -----------------------------------------------------------------------------
extern "C" void kernel_launch(void* const* d_in, const int* in_sizes, int n_in,
                              void* d_out, int out_size, void* d_ws, size_t ws_size,
                              hipStream_t stream)
{
    const float* x     = (const float*)d_in[0];
    const float* wq    = (const float*)d_in[1];
    const float* wk    = (const float*)d_in[2];
    const float* wv    = (const float*)d_in[3];
    const float* wproj = (const float*)d_in[4];
    const float* bproj = (const float*)d_in[5];
    const float* w1    = (const float*)d_in[6];
    const float* b1    = (const float*)d_in[7];
    const float* w2    = (const float*)d_in[8];
    const float* b2    = (const float*)d_in[9];
    const float* ln1g  = (const float*)d_in[10];
    const float* ln1b  = (const float*)d_in[11];
    const float* ln2g  = (const float*)d_in[12];
    const float* ln2b  = (const float*)d_in[13];

    // Workspace:
    //  [0,64M)    h,q,k,v (16 MB each; q/k/v contiguous for merged-QKV scatter)
    //             -> later mid (BT x 2048 bf16)
    //  [64,80M)   o (B,T,C bf16)
    //  [80,96M)   h2 (bf16)
    //  [96,102M)  Wt: qkvt[1536][512] | projt[512][512] | w1t[2048][512] | w2t[512][2048]
    //  x1 (f32) lives in d_out (same-thread RMW in final epilogue)
    char* ws = (char*)d_ws;
    bf16*  h    = (bf16*)(ws + 0);
    bf16*  q    = (bf16*)(ws + ((size_t)16 << 20));
    bf16*  k    = (bf16*)(ws + ((size_t)32 << 20));
    bf16*  v    = (bf16*)(ws + ((size_t)48 << 20));   // (B,H,D,T)
    bf16*  mid  = (bf16*)(ws + 0);
    bf16*  o    = (bf16*)(ws + ((size_t)64 << 20));
    bf16*  h2   = (bf16*)(ws + ((size_t)80 << 20));
    bf16*  wt   = (bf16*)(ws + ((size_t)96 << 20));
    bf16*  projt = wt + (size_t)1536 * 512;
    bf16*  w1t   = wt + (size_t)2048 * 512;
    bf16*  w2t   = wt + (size_t)4096 * 512;
    float* x1    = (float*)d_out;

    // 0. all weight transposes (f32 -> bf16, [N][K])
    transpose_all<<<768, 256, 0, stream>>>(wq, wk, wv, wproj, w1, w2, wt);

    // 1. h = LN1(x)
    ln_kernel<<<BT, 256, 0, stream>>>(x, ln1g, ln1b, h);

    // 2. q|k|v = h @ wqkv  (one N=1536 GEMM; v written (B,H,D,T))
    mfma_gemm<true,  false, true ><<<dim3(12, 128), 256, 0, stream>>>(h, wt, nullptr, nullptr, q, 1536, 512);

    // 3. o = flash-attn(q,k,v) -> (B,T,C)
    attn_kernel<<<dim3(8, B_ * H_), 256, 0, stream>>>(q, k, v, o);

    // 4. x1 = x + o @ w_proj + b_proj   (x1 = d_out, f32)
    mfma_gemm<false, false, false><<<dim3(4, 128), 256, 0, stream>>>(o, projt, bproj, x, x1, 512, 512);

    // 5. h2 = LN2(x1)
    ln_kernel<<<BT, 256, 0, stream>>>(x1, ln2g, ln2b, h2);

    // 6. mid = relu(h2 @ w1 + b1)
    mfma_gemm<false, true,  true ><<<dim3(16, 128), 256, 0, stream>>>(h2, w1t, b1, nullptr, mid, 2048, 512);

    // 7. out = x1 + mid @ w2 + b2   (in-place on d_out)
    mfma_gemm<false, false, false><<<dim3(4, 128), 256, 0, stream>>>(mid, w2t, b2, x1, (float*)d_out, 512, 2048);
}

// Round 6
// 467.364 us; speedup vs baseline: 1.2841x; 1.2841x over previous
//
#include <hip/hip_runtime.h>
#include <hip/hip_bf16.h>

// Transformer block: B=32 T=512 C=512 H=8 D=64
// Round 6: GEMM K-loop = AITER-style producer/consumer pipeline:
//   buffer_load (global->VGPR, issued BEFORE the MFMA block)
//   -> MFMA on current LDS buffer -> ds_write VGPR->LDS (other buffer)
//   -> single barrier.  The vmcnt wait lands on the ds_write, ~300 MFMA
// cycles after issue, so the pre-barrier vmcnt(0) is already satisfied --
// removes the full-latency drain that capped rounds 3-4 (MfmaUtil ~13%).
// Round-5's no-LDS variant (146 us) reverted. Epilogues/attention unchanged.

#define B_  32
#define T_  512
#define C_  512
#define H_  8
#define D_  64
#define BT  (B_*T_)      // 16384 rows
#define CF  2048         // 4*C

typedef __hip_bfloat16 bf16;
typedef __attribute__((ext_vector_type(8))) short bf16x8;   // 8 bf16 (4 VGPRs)
typedef __attribute__((ext_vector_type(4))) float f32x4;
typedef __attribute__((ext_vector_type(4))) short short4v;

__device__ __forceinline__ float bf2f(bf16 x) { return __bfloat162float(x); }
__device__ __forceinline__ bf16  f2bf(float x){ return __float2bfloat16(x); }
__device__ __forceinline__ short f2bf_bits(float f){
    bf16 h = __float2bfloat16(f);
    return *reinterpret_cast<short*>(&h);
}
__device__ __forceinline__ float bfbits2f(short s){
    unsigned u = ((unsigned)(unsigned short)s) << 16;
    return __uint_as_float(u);
}

// ---------------- All weight transposes in one launch ------------------------
__global__ __launch_bounds__(256) void transpose_all(const float* __restrict__ wq,
                                                     const float* __restrict__ wk,
                                                     const float* __restrict__ wv,
                                                     const float* __restrict__ wproj,
                                                     const float* __restrict__ w1,
                                                     const float* __restrict__ w2,
                                                     bf16* __restrict__ wt)
{
    const int t = blockIdx.x;
    const float* src; int K, Nn, k0, n0; size_t dstoff;
    if (t < 192) {
        const int which = t / 64, w = t % 64, hh = w >> 3, kt = w & 7;
        src = (which == 0 ? wq : which == 1 ? wk : wv) + (size_t)hh * 512 * 64;
        K = 512; Nn = 64; k0 = kt * 64; n0 = 0;
        dstoff = (size_t)(which * 512 + hh * 64) * 512;
    } else if (t < 256) {
        const int i = t - 192;
        src = wproj; K = 512; Nn = 512; n0 = (i & 7) * 64; k0 = (i >> 3) * 64;
        dstoff = (size_t)1536 * 512;
    } else if (t < 512) {
        const int i = t - 256;
        src = w1; K = 512; Nn = 2048; n0 = (i & 31) * 64; k0 = (i >> 5) * 64;
        dstoff = (size_t)2048 * 512;
    } else {
        const int i = t - 512;
        src = w2; K = 2048; Nn = 512; n0 = (i & 7) * 64; k0 = (i >> 3) * 64;
        dstoff = (size_t)2048 * 512 + (size_t)2048 * 512;
    }

    __shared__ float tl[64][65];
    const int tid = threadIdx.x;
    #pragma unroll
    for (int j = 0; j < 16; ++j) {
        const int e = j * 256 + tid, r = e >> 6, c = e & 63;
        tl[r][c] = src[(size_t)(k0 + r) * Nn + n0 + c];
    }
    __syncthreads();
    #pragma unroll
    for (int j = 0; j < 16; ++j) {
        const int e = j * 256 + tid, n = e >> 6, kk = e & 63;
        wt[dstoff + (size_t)(n0 + n) * K + k0 + kk] = f2bf(tl[kk][n]);
    }
}

// ---------------- LayerNorm: one block per row (C=512), 256 threads ----------
__global__ __launch_bounds__(256) void ln_kernel(const float* __restrict__ x,
                                                 const float* __restrict__ g,
                                                 const float* __restrict__ b,
                                                 bf16* __restrict__ out)
{
    const int row = blockIdx.x;
    const int tid = threadIdx.x;
    const float* xr = x + (size_t)row * C_;
    float v0 = xr[tid], v1 = xr[tid + 256];

    __shared__ float red[4];

    float s = v0 + v1;
    #pragma unroll
    for (int off = 32; off > 0; off >>= 1) s += __shfl_down(s, off, 64);
    if ((tid & 63) == 0) red[tid >> 6] = s;
    __syncthreads();
    const float mean = (red[0] + red[1] + red[2] + red[3]) * (1.0f / C_);
    __syncthreads();

    float d0 = v0 - mean, d1 = v1 - mean;
    float vs = d0 * d0 + d1 * d1;
    #pragma unroll
    for (int off = 32; off > 0; off >>= 1) vs += __shfl_down(vs, off, 64);
    if ((tid & 63) == 0) red[tid >> 6] = vs;
    __syncthreads();
    const float var  = (red[0] + red[1] + red[2] + red[3]) * (1.0f / C_);
    const float rstd = rsqrtf(var + 1e-5f);

    bf16* orow = out + (size_t)row * C_;
    orow[tid]       = f2bf(d0 * rstd * g[tid]       + b[tid]);
    orow[tid + 256] = f2bf(d1 * rstd * g[tid + 256] + b[tid + 256]);
}

// ---------------- MFMA GEMM: C[M,N] = A[M,K](bf16) * Bt[N,K](bf16)^T ---------
// 128x128 tile, BK=32, 256 threads = 4 waves (2x2 of 64x64).
// Ping-pong LDS (2 x 8 KB per operand = 32 KB total), XOR-swizzled 16B chunks
// (phys = log ^ ((row>>1)&3)) for conflict-free b128 frag reads.
// Pipeline per iter: global->VGPR prefetch (k+1) | ds_read+16 MFMA (k) |
// ds_write (k+1) | one barrier.
// Default: C^T accumulation (mfma(b,a)) -> packed epilogue stores.
// QKV: N=1536, q/k -> (B,H,T,D) dd-packed; v third -> (B,H,D,T) t-packed.
template<bool QKV, bool RELU, bool OUT_BF16>
__global__ __launch_bounds__(256, 3) void mfma_gemm(const bf16* __restrict__ A,
                                                    const bf16* __restrict__ Bt,
                                                    const float* __restrict__ bias,
                                                    const float* __restrict__ res,
                                                    void* __restrict__ outp,
                                                    int N, int K)
{
    __shared__ __align__(16) bf16 As[2 * 128 * 32];
    __shared__ __align__(16) bf16 Bs[2 * 128 * 32];

    const int tid  = threadIdx.x;
    const int wave = tid >> 6, lane = tid & 63;
    const int l16  = lane & 15, quad = lane >> 4;
    const int wm   = wave >> 1, wn = wave & 1;
    const int tm   = blockIdx.y * 128, tn = blockIdx.x * 128;
    const bool vblk = QKV && (tn >= 1024);     // v third of the merged QKV GEMM

    // staging maps: each thread owns 2 rows (r, r+64), one 16B chunk each
    const int rowS = tid >> 2, pS = tid & 3;
    const int c0 = pS ^ ((rowS >> 1) & 3);             // global chunk, row rowS
    const int c1 = pS ^ (((rowS + 64) >> 1) & 3);      // global chunk, row rowS+64
    const bf16* gA0 = A  + (size_t)(tm + rowS) * K + c0 * 8;
    const bf16* gA1 = A  + (size_t)(tm + rowS + 64) * K + c1 * 8;
    const bf16* gB0 = Bt + (size_t)(tn + rowS) * K + c0 * 8;
    const bf16* gB1 = Bt + (size_t)(tn + rowS + 64) * K + c1 * 8;
    const int ldsOff0 = rowS * 32 + pS * 8;            // phys layout
    const int ldsOff1 = (rowS + 64) * 32 + pS * 8;

    f32x4 acc[4][4];
    #pragma unroll
    for (int i = 0; i < 4; ++i)
        #pragma unroll
        for (int j = 0; j < 4; ++j) acc[i][j] = (f32x4){0.f, 0.f, 0.f, 0.f};

    // preload tile 0 -> VGPR -> LDS buf 0
    uint4 pa0 = *(const uint4*)gA0, pa1 = *(const uint4*)gA1;
    uint4 pb0 = *(const uint4*)gB0, pb1 = *(const uint4*)gB1;
    *(uint4*)&As[ldsOff0] = pa0;  *(uint4*)&As[ldsOff1] = pa1;
    *(uint4*)&Bs[ldsOff0] = pb0;  *(uint4*)&Bs[ldsOff1] = pb1;
    __syncthreads();

    const int nIter = K >> 5;
    for (int it = 0; it < nIter; ++it) {
        const int cur = (it & 1) * 4096, nxt = 4096 - cur;
        const bool more = (it + 1 < nIter);

        // 1. issue next-tile global loads (result needed only at step 3)
        if (more) {
            const int ko = (it + 1) << 5;
            pa0 = *(const uint4*)(gA0 + ko);  pa1 = *(const uint4*)(gA1 + ko);
            pb0 = *(const uint4*)(gB0 + ko);  pb1 = *(const uint4*)(gB1 + ko);
        }

        // 2. consume current buffer: frag reads + 16 MFMA
        bf16x8 af[4], bfr[4];
        #pragma unroll
        for (int mf = 0; mf < 4; ++mf) {
            const int r = wm * 64 + mf * 16 + l16;
            const int p = quad ^ ((r >> 1) & 3);
            af[mf] = *(const bf16x8*)&As[cur + r * 32 + p * 8];
        }
        #pragma unroll
        for (int nf = 0; nf < 4; ++nf) {
            const int r = wn * 64 + nf * 16 + l16;
            const int p = quad ^ ((r >> 1) & 3);
            bfr[nf] = *(const bf16x8*)&Bs[cur + r * 32 + p * 8];
        }
        if (vblk) {
            #pragma unroll
            for (int mf = 0; mf < 4; ++mf)
                #pragma unroll
                for (int nf = 0; nf < 4; ++nf)
                    acc[mf][nf] = __builtin_amdgcn_mfma_f32_16x16x32_bf16(af[mf], bfr[nf], acc[mf][nf], 0, 0, 0);
        } else {
            #pragma unroll
            for (int mf = 0; mf < 4; ++mf)
                #pragma unroll
                for (int nf = 0; nf < 4; ++nf)
                    acc[mf][nf] = __builtin_amdgcn_mfma_f32_16x16x32_bf16(bfr[nf], af[mf], acc[mf][nf], 0, 0, 0);
        }

        // 3. stage next tile into the other buffer; one barrier
        if (more) {
            *(uint4*)&As[nxt + ldsOff0] = pa0;  *(uint4*)&As[nxt + ldsOff1] = pa1;
            *(uint4*)&Bs[nxt + ldsOff0] = pb0;  *(uint4*)&Bs[nxt + ldsOff1] = pb1;
            __syncthreads();
        }
    }

    if (QKV) {
        bf16* qkv = (bf16*)outp;                 // q base; k at +8M elems, v at +16M
        if (!vblk) {
            const int which = tn >> 9;           // 0=q, 1=k
            bf16* dst = qkv + (size_t)which * (8u << 20);
            #pragma unroll
            for (int mf = 0; mf < 4; ++mf) {
                const int m = tm + wm * 64 + mf * 16 + l16;   // token (C^T: col=m)
                const int bb = m >> 9, t = m & 511;
                #pragma unroll
                for (int nf = 0; nf < 4; ++nf) {
                    const int nb = tn + wn * 64 + nf * 16 + quad * 4;
                    const int hh = (nb >> 6) & 7, dd = nb & 63;
                    short4v pk;
                    #pragma unroll
                    for (int r = 0; r < 4; ++r) pk[r] = f2bf_bits(acc[mf][nf][r]);
                    *(short4v*)&dst[((size_t)(bb * 8 + hh) * 512 + t) * 64 + dd] = pk;
                }
            }
        } else {
            bf16* dst = qkv + (size_t)2 * (8u << 20);
            #pragma unroll
            for (int mf = 0; mf < 4; ++mf) {
                const int mb = tm + wm * 64 + mf * 16 + quad * 4;   // token base
                const int bb = mb >> 9, t = mb & 511;
                #pragma unroll
                for (int nf = 0; nf < 4; ++nf) {
                    const int n = tn + wn * 64 + nf * 16 + l16;
                    const int hh = (n >> 6) & 7, dd = n & 63;
                    short4v pk;
                    #pragma unroll
                    for (int r = 0; r < 4; ++r) pk[r] = f2bf_bits(acc[mf][nf][r]);
                    *(short4v*)&dst[((size_t)(bb * 8 + hh) * 64 + dd) * 512 + t] = pk;
                }
            }
        }
    } else {
        #pragma unroll
        for (int mf = 0; mf < 4; ++mf) {
            const int m = tm + wm * 64 + mf * 16 + l16;             // C^T: col=m
            #pragma unroll
            for (int nf = 0; nf < 4; ++nf) {
                const int nb = tn + wn * 64 + nf * 16 + quad * 4;   // 4 consecutive n
                f32x4 a = acc[mf][nf];
                if (bias) a += *(const f32x4*)&bias[nb];
                if (RELU) {
                    #pragma unroll
                    for (int r = 0; r < 4; ++r) a[r] = fmaxf(a[r], 0.0f);
                }
                if (res)  a += *(const f32x4*)&res[(size_t)m * N + nb];
                if (OUT_BF16) {
                    short4v pk;
                    #pragma unroll
                    for (int r = 0; r < 4; ++r) pk[r] = f2bf_bits(a[r]);
                    *(short4v*)&((bf16*)outp)[(size_t)m * N + nb] = pk;
                } else {
                    *(f32x4*)&((float*)outp)[(size_t)m * N + nb] = a;
                }
            }
        }
    }
}

// ---------------- Flash attention: MFMA 16x16x32 bf16 (unchanged) ------------
__global__ __launch_bounds__(256) void attn_kernel(const bf16* __restrict__ q,
                                                   const bf16* __restrict__ kM,
                                                   const bf16* __restrict__ vT,
                                                   bf16* __restrict__ o)
{
    __shared__ __align__(16) bf16 Ks[64][72];
    __shared__ __align__(16) bf16 Vt[64][72];
    __shared__ __align__(16) bf16 Pw[4][16][72];

    const int qt   = gridDim.x - 1 - blockIdx.x;
    const int bh   = blockIdx.y;
    const int tid  = threadIdx.x;
    const int wave = tid >> 6, lane = tid & 63;
    const int l16  = lane & 15, quad = lane >> 4;
    const int qw   = qt * 64 + wave * 16;

    const float scale = 0.04419417382415922f;  // C^-0.5 (reference uses n_embd)
    bf16x8 qa[2];
    #pragma unroll
    for (int c = 0; c < 2; ++c) {
        const bf16* qp = q + ((size_t)bh * T_ + qw + l16) * 64 + c * 32 + quad * 8;
        bf16x8 t = *(const bf16x8*)qp;
        #pragma unroll
        for (int j = 0; j < 8; ++j) t[j] = f2bf_bits(bfbits2f(t[j]) * scale);
        qa[c] = t;
    }

    float m_i[4], l_i[4];
    f32x4 Of[4];
    #pragma unroll
    for (int r = 0; r < 4; ++r) { m_i[r] = -1e30f; l_i[r] = 0.0f; }
    #pragma unroll
    for (int f = 0; f < 4; ++f) Of[f] = (f32x4){0.f, 0.f, 0.f, 0.f};

    for (int kt = 0; kt <= qt; ++kt) {
        const int k0 = kt * 64;
        __syncthreads();
        #pragma unroll
        for (int c2 = 0; c2 < 2; ++c2) {
            const int ch = tid + c2 * 256;
            const int row = ch >> 3, e8 = (ch & 7) * 8;
            *(uint4*)&Ks[row][e8] = *(const uint4*)(kM + ((size_t)bh * T_ + k0 + row) * 64 + e8);
            *(uint4*)&Vt[row][e8] = *(const uint4*)(vT + ((size_t)bh * 64 + row) * T_ + k0 + e8);
        }
        __syncthreads();

        f32x4 Sf[4];
        #pragma unroll
        for (int kf = 0; kf < 4; ++kf) {
            bf16x8 b0 = *(const bf16x8*)&Ks[kf * 16 + l16][quad * 8];
            bf16x8 b1 = *(const bf16x8*)&Ks[kf * 16 + l16][32 + quad * 8];
            f32x4 z = (f32x4){0.f, 0.f, 0.f, 0.f};
            z = __builtin_amdgcn_mfma_f32_16x16x32_bf16(qa[0], b0, z, 0, 0, 0);
            z = __builtin_amdgcn_mfma_f32_16x16x32_bf16(qa[1], b1, z, 0, 0, 0);
            Sf[kf] = z;
        }

        if (kt == qt) {
            #pragma unroll
            for (int kf = 0; kf < 4; ++kf)
                #pragma unroll
                for (int r = 0; r < 4; ++r)
                    if (k0 + kf * 16 + l16 > qw + quad * 4 + r) Sf[kf][r] = -1e30f;
        }

        float mnew[4], alpha[4];
        #pragma unroll
        for (int r = 0; r < 4; ++r) {
            float v = fmaxf(fmaxf(Sf[0][r], Sf[1][r]), fmaxf(Sf[2][r], Sf[3][r]));
            v = fmaxf(v, __shfl_xor(v, 1, 64));
            v = fmaxf(v, __shfl_xor(v, 2, 64));
            v = fmaxf(v, __shfl_xor(v, 4, 64));
            v = fmaxf(v, __shfl_xor(v, 8, 64));
            mnew[r]  = fmaxf(m_i[r], v);
            alpha[r] = __expf(m_i[r] - mnew[r]);
            m_i[r]   = mnew[r];
        }

        float rs[4] = {0.f, 0.f, 0.f, 0.f};
        #pragma unroll
        for (int kf = 0; kf < 4; ++kf) {
            #pragma unroll
            for (int r = 0; r < 4; ++r) {
                float p = __expf(Sf[kf][r] - mnew[r]);
                rs[r] += p;
                Pw[wave][quad * 4 + r][kf * 16 + l16] = f2bf(p);
            }
        }
        #pragma unroll
        for (int r = 0; r < 4; ++r) {
            rs[r] += __shfl_xor(rs[r], 1, 64);
            rs[r] += __shfl_xor(rs[r], 2, 64);
            rs[r] += __shfl_xor(rs[r], 4, 64);
            rs[r] += __shfl_xor(rs[r], 8, 64);
            l_i[r] = l_i[r] * alpha[r] + rs[r];
        }
        #pragma unroll
        for (int f = 0; f < 4; ++f)
            #pragma unroll
            for (int r = 0; r < 4; ++r)
                Of[f][r] *= alpha[r];

        bf16x8 pa0 = *(const bf16x8*)&Pw[wave][l16][quad * 8];
        bf16x8 pa1 = *(const bf16x8*)&Pw[wave][l16][32 + quad * 8];
        #pragma unroll
        for (int f = 0; f < 4; ++f) {
            bf16x8 vb0 = *(const bf16x8*)&Vt[f * 16 + l16][quad * 8];
            bf16x8 vb1 = *(const bf16x8*)&Vt[f * 16 + l16][32 + quad * 8];
            Of[f] = __builtin_amdgcn_mfma_f32_16x16x32_bf16(pa0, vb0, Of[f], 0, 0, 0);
            Of[f] = __builtin_amdgcn_mfma_f32_16x16x32_bf16(pa1, vb1, Of[f], 0, 0, 0);
        }
    }

    const int b = bh >> 3, hh = bh & 7;
    #pragma unroll
    for (int r = 0; r < 4; ++r) {
        const float inv = 1.0f / l_i[r];
        const int t = qw + quad * 4 + r;
        #pragma unroll
        for (int f = 0; f < 4; ++f)
            o[((size_t)b * T_ + t) * C_ + hh * 64 + f * 16 + l16] = f2bf(Of[f][r] * inv);
    }
}

// -----------------------------------------------------------------------------
extern "C" void kernel_launch(void* const* d_in, const int* in_sizes, int n_in,
                              void* d_out, int out_size, void* d_ws, size_t ws_size,
                              hipStream_t stream)
{
    const float* x     = (const float*)d_in[0];
    const float* wq    = (const float*)d_in[1];
    const float* wk    = (const float*)d_in[2];
    const float* wv    = (const float*)d_in[3];
    const float* wproj = (const float*)d_in[4];
    const float* bproj = (const float*)d_in[5];
    const float* w1    = (const float*)d_in[6];
    const float* b1    = (const float*)d_in[7];
    const float* w2    = (const float*)d_in[8];
    const float* b2    = (const float*)d_in[9];
    const float* ln1g  = (const float*)d_in[10];
    const float* ln1b  = (const float*)d_in[11];
    const float* ln2g  = (const float*)d_in[12];
    const float* ln2b  = (const float*)d_in[13];

    // Workspace:
    //  [0,64M)    h,q,k,v (16 MB each; q/k/v contiguous for merged-QKV scatter)
    //             -> later mid (BT x 2048 bf16)
    //  [64,80M)   o (B,T,C bf16)
    //  [80,96M)   h2 (bf16)
    //  [96,102M)  Wt: qkvt[1536][512] | projt[512][512] | w1t[2048][512] | w2t[512][2048]
    //  x1 (f32) lives in d_out (same-thread RMW in final epilogue)
    char* ws = (char*)d_ws;
    bf16*  h    = (bf16*)(ws + 0);
    bf16*  q    = (bf16*)(ws + ((size_t)16 << 20));
    bf16*  k    = (bf16*)(ws + ((size_t)32 << 20));
    bf16*  v    = (bf16*)(ws + ((size_t)48 << 20));   // (B,H,D,T)
    bf16*  mid  = (bf16*)(ws + 0);
    bf16*  o    = (bf16*)(ws + ((size_t)64 << 20));
    bf16*  h2   = (bf16*)(ws + ((size_t)80 << 20));
    bf16*  wt   = (bf16*)(ws + ((size_t)96 << 20));
    bf16*  projt = wt + (size_t)1536 * 512;
    bf16*  w1t   = wt + (size_t)2048 * 512;
    bf16*  w2t   = wt + (size_t)4096 * 512;
    float* x1    = (float*)d_out;

    // 0. all weight transposes (f32 -> bf16, [N][K])
    transpose_all<<<768, 256, 0, stream>>>(wq, wk, wv, wproj, w1, w2, wt);

    // 1. h = LN1(x)
    ln_kernel<<<BT, 256, 0, stream>>>(x, ln1g, ln1b, h);

    // 2. q|k|v = h @ wqkv  (one N=1536 GEMM; v written (B,H,D,T))
    mfma_gemm<true,  false, true ><<<dim3(12, 128), 256, 0, stream>>>(h, wt, nullptr, nullptr, q, 1536, 512);

    // 3. o = flash-attn(q,k,v) -> (B,T,C)
    attn_kernel<<<dim3(8, B_ * H_), 256, 0, stream>>>(q, k, v, o);

    // 4. x1 = x + o @ w_proj + b_proj   (x1 = d_out, f32)
    mfma_gemm<false, false, false><<<dim3(4, 128), 256, 0, stream>>>(o, projt, bproj, x, x1, 512, 512);

    // 5. h2 = LN2(x1)
    ln_kernel<<<BT, 256, 0, stream>>>(x1, ln2g, ln2b, h2);

    // 6. mid = relu(h2 @ w1 + b1)
    mfma_gemm<false, true,  true ><<<dim3(16, 128), 256, 0, stream>>>(h2, w1t, b1, nullptr, mid, 2048, 512);

    // 7. out = x1 + mid @ w2 + b2   (in-place on d_out)
    mfma_gemm<false, false, false><<<dim3(4, 128), 256, 0, stream>>>(mid, w2t, b2, x1, (float*)d_out, 512, 2048);
}

// Round 7
// 435.185 us; speedup vs baseline: 1.3790x; 1.0739x over previous
//
#include <hip/hip_runtime.h>
#include <hip/hip_bf16.h>

// Transformer block: B=32 T=512 C=512 H=8 D=64
// Round 7: GEMM = round-4 tile (128x128, BK=32, XOR swizzle, C^T epilogues)
// + LDS double-buffer pipeline via global_load_lds into FOUR DISTINCT shared
// arrays: issue tile k+1 -> other buffer BEFORE the MFMA block on the current
// buffer, so the barrier's implicit vmcnt(0) waits on loads issued one full
// compute block earlier (round 4 issued then immediately drained = full
// latency exposed; round 6's VGPR prefetch spilled to scratch, 344 MB/dispatch
// writeback). No prefetch VGPRs -> no spill.

#define B_  32
#define T_  512
#define C_  512
#define H_  8
#define D_  64
#define BT  (B_*T_)      // 16384 rows
#define CF  2048         // 4*C

typedef __hip_bfloat16 bf16;
typedef __attribute__((ext_vector_type(8))) short bf16x8;   // 8 bf16 (4 VGPRs)
typedef __attribute__((ext_vector_type(4))) float f32x4;
typedef __attribute__((ext_vector_type(4))) short short4v;

__device__ __forceinline__ float bf2f(bf16 x) { return __bfloat162float(x); }
__device__ __forceinline__ bf16  f2bf(float x){ return __float2bfloat16(x); }
__device__ __forceinline__ short f2bf_bits(float f){
    bf16 h = __float2bfloat16(f);
    return *reinterpret_cast<short*>(&h);
}
__device__ __forceinline__ float bfbits2f(short s){
    unsigned u = ((unsigned)(unsigned short)s) << 16;
    return __uint_as_float(u);
}

#define AS_G __attribute__((address_space(1)))
#define AS_L __attribute__((address_space(3)))

// ---------------- All weight transposes in one launch ------------------------
__global__ __launch_bounds__(256) void transpose_all(const float* __restrict__ wq,
                                                     const float* __restrict__ wk,
                                                     const float* __restrict__ wv,
                                                     const float* __restrict__ wproj,
                                                     const float* __restrict__ w1,
                                                     const float* __restrict__ w2,
                                                     bf16* __restrict__ wt)
{
    const int t = blockIdx.x;
    const float* src; int K, Nn, k0, n0; size_t dstoff;
    if (t < 192) {
        const int which = t / 64, w = t % 64, hh = w >> 3, kt = w & 7;
        src = (which == 0 ? wq : which == 1 ? wk : wv) + (size_t)hh * 512 * 64;
        K = 512; Nn = 64; k0 = kt * 64; n0 = 0;
        dstoff = (size_t)(which * 512 + hh * 64) * 512;
    } else if (t < 256) {
        const int i = t - 192;
        src = wproj; K = 512; Nn = 512; n0 = (i & 7) * 64; k0 = (i >> 3) * 64;
        dstoff = (size_t)1536 * 512;
    } else if (t < 512) {
        const int i = t - 256;
        src = w1; K = 512; Nn = 2048; n0 = (i & 31) * 64; k0 = (i >> 5) * 64;
        dstoff = (size_t)2048 * 512;
    } else {
        const int i = t - 512;
        src = w2; K = 2048; Nn = 512; n0 = (i & 7) * 64; k0 = (i >> 3) * 64;
        dstoff = (size_t)2048 * 512 + (size_t)2048 * 512;
    }

    __shared__ float tl[64][65];
    const int tid = threadIdx.x;
    #pragma unroll
    for (int j = 0; j < 16; ++j) {
        const int e = j * 256 + tid, r = e >> 6, c = e & 63;
        tl[r][c] = src[(size_t)(k0 + r) * Nn + n0 + c];
    }
    __syncthreads();
    #pragma unroll
    for (int j = 0; j < 16; ++j) {
        const int e = j * 256 + tid, n = e >> 6, kk = e & 63;
        wt[dstoff + (size_t)(n0 + n) * K + k0 + kk] = f2bf(tl[kk][n]);
    }
}

// ---------------- LayerNorm: one block per row (C=512), 256 threads ----------
__global__ __launch_bounds__(256) void ln_kernel(const float* __restrict__ x,
                                                 const float* __restrict__ g,
                                                 const float* __restrict__ b,
                                                 bf16* __restrict__ out)
{
    const int row = blockIdx.x;
    const int tid = threadIdx.x;
    const float* xr = x + (size_t)row * C_;
    float v0 = xr[tid], v1 = xr[tid + 256];

    __shared__ float red[4];

    float s = v0 + v1;
    #pragma unroll
    for (int off = 32; off > 0; off >>= 1) s += __shfl_down(s, off, 64);
    if ((tid & 63) == 0) red[tid >> 6] = s;
    __syncthreads();
    const float mean = (red[0] + red[1] + red[2] + red[3]) * (1.0f / C_);
    __syncthreads();

    float d0 = v0 - mean, d1 = v1 - mean;
    float vs = d0 * d0 + d1 * d1;
    #pragma unroll
    for (int off = 32; off > 0; off >>= 1) vs += __shfl_down(vs, off, 64);
    if ((tid & 63) == 0) red[tid >> 6] = vs;
    __syncthreads();
    const float var  = (red[0] + red[1] + red[2] + red[3]) * (1.0f / C_);
    const float rstd = rsqrtf(var + 1e-5f);

    bf16* orow = out + (size_t)row * C_;
    orow[tid]       = f2bf(d0 * rstd * g[tid]       + b[tid]);
    orow[tid + 256] = f2bf(d1 * rstd * g[tid + 256] + b[tid + 256]);
}

// ---------------- MFMA GEMM: C[M,N] = A[M,K](bf16) * Bt[N,K](bf16)^T ---------
// 128x128 tile, BK=32, 256 threads = 4 waves (2x2 of 64x64).
// Double-buffered global_load_lds (4 distinct shared arrays, 32 KB total),
// XOR-swizzled 16B chunks (phys = log ^ ((row>>1)&3)) -> conflict-free b128.
// Per ping-pong step: issue stage(next -> other buf) | ds_read+16 MFMA (cur) |
// barrier (its vmcnt(0) waits loads issued one compute-block earlier).
// Default: C^T accumulation (mfma(b,a)) -> packed epilogue stores.
// QKV: N=1536, q/k -> (B,H,T,D) dd-packed; v third -> (B,H,D,T) t-packed.

#define STAGE(as, bs, k0)                                                                  \
    do {                                                                                   \
        __builtin_amdgcn_global_load_lds((const AS_G void*)(gA0 + (k0)),                   \
                                         (AS_L void*)&as[d0], 16, 0, 0);                   \
        __builtin_amdgcn_global_load_lds((const AS_G void*)(gA1 + (k0)),                   \
                                         (AS_L void*)&as[d1], 16, 0, 0);                   \
        __builtin_amdgcn_global_load_lds((const AS_G void*)(gB0 + (k0)),                   \
                                         (AS_L void*)&bs[d0], 16, 0, 0);                   \
        __builtin_amdgcn_global_load_lds((const AS_G void*)(gB1 + (k0)),                   \
                                         (AS_L void*)&bs[d1], 16, 0, 0);                   \
    } while (0)

#define COMPUTE(as, bs)                                                                    \
    do {                                                                                   \
        bf16x8 af[4], bfr[4];                                                              \
        _Pragma("unroll")                                                                  \
        for (int mf = 0; mf < 4; ++mf) {                                                   \
            const int r = wm * 64 + mf * 16 + l16;                                         \
            const int p = quad ^ ((r >> 1) & 3);                                           \
            af[mf] = *(const bf16x8*)&as[r * 32 + p * 8];                                  \
        }                                                                                  \
        _Pragma("unroll")                                                                  \
        for (int nf = 0; nf < 4; ++nf) {                                                   \
            const int r = wn * 64 + nf * 16 + l16;                                         \
            const int p = quad ^ ((r >> 1) & 3);                                           \
            bfr[nf] = *(const bf16x8*)&bs[r * 32 + p * 8];                                 \
        }                                                                                  \
        if (vblk) {                                                                        \
            _Pragma("unroll")                                                              \
            for (int mf = 0; mf < 4; ++mf)                                                 \
                _Pragma("unroll")                                                          \
                for (int nf = 0; nf < 4; ++nf)                                             \
                    acc[mf][nf] = __builtin_amdgcn_mfma_f32_16x16x32_bf16(                 \
                        af[mf], bfr[nf], acc[mf][nf], 0, 0, 0);                            \
        } else {                                                                           \
            _Pragma("unroll")                                                              \
            for (int mf = 0; mf < 4; ++mf)                                                 \
                _Pragma("unroll")                                                          \
                for (int nf = 0; nf < 4; ++nf)                                             \
                    acc[mf][nf] = __builtin_amdgcn_mfma_f32_16x16x32_bf16(                 \
                        bfr[nf], af[mf], acc[mf][nf], 0, 0, 0);                            \
        }                                                                                  \
    } while (0)

template<bool QKV, bool RELU, bool OUT_BF16>
__global__ __launch_bounds__(256, 3) void mfma_gemm(const bf16* __restrict__ A,
                                                    const bf16* __restrict__ Bt,
                                                    const float* __restrict__ bias,
                                                    const float* __restrict__ res,
                                                    void* __restrict__ outp,
                                                    int N, int K)
{
    __shared__ __align__(16) bf16 As0[128 * 32];
    __shared__ __align__(16) bf16 Bs0[128 * 32];
    __shared__ __align__(16) bf16 As1[128 * 32];
    __shared__ __align__(16) bf16 Bs1[128 * 32];

    const int tid  = threadIdx.x;
    const int wave = tid >> 6, lane = tid & 63;
    const int l16  = lane & 15, quad = lane >> 4;
    const int wm   = wave >> 1, wn = wave & 1;
    const int tm   = blockIdx.y * 128, tn = blockIdx.x * 128;
    const bool vblk = QKV && (tn >= 1024);     // v third of the merged QKV GEMM

    // staging maps: each thread owns rows rowS and rowS+64, one 16B chunk each
    const int rowS = tid >> 2, pS = tid & 3;
    const int cA0 = pS ^ ((rowS >> 1) & 3);            // logical chunk for row rowS
    const int cA1 = pS ^ (((rowS + 64) >> 1) & 3);     // for row rowS+64
    const bf16* gA0 = A  + (size_t)(tm + rowS) * K + cA0 * 8;
    const bf16* gA1 = A  + (size_t)(tm + rowS + 64) * K + cA1 * 8;
    const bf16* gB0 = Bt + (size_t)(tn + rowS) * K + cA0 * 8;
    const bf16* gB1 = Bt + (size_t)(tn + rowS + 64) * K + cA1 * 8;
    const int d0 = tid * 8;                            // LDS elem offsets (phys layout)
    const int d1 = (256 + tid) * 8;

    f32x4 acc[4][4];
    #pragma unroll
    for (int i = 0; i < 4; ++i)
        #pragma unroll
        for (int j = 0; j < 4; ++j) acc[i][j] = (f32x4){0.f, 0.f, 0.f, 0.f};

    STAGE(As0, Bs0, 0);
    __syncthreads();

    const int nIter = K >> 5;   // 16 or 64 -- always even
    for (int it = 0; it < nIter; it += 2) {
        STAGE(As1, Bs1, (it + 1) << 5);
        COMPUTE(As0, Bs0);
        __syncthreads();
        if (it + 2 < nIter) STAGE(As0, Bs0, (it + 2) << 5);
        COMPUTE(As1, Bs1);
        __syncthreads();
    }

    if (QKV) {
        bf16* qkv = (bf16*)outp;                 // q base; k at +8M elems, v at +16M
        if (!vblk) {
            const int which = tn >> 9;           // 0=q, 1=k
            bf16* dst = qkv + (size_t)which * (8u << 20);
            #pragma unroll
            for (int mf = 0; mf < 4; ++mf) {
                const int m = tm + wm * 64 + mf * 16 + l16;   // token (C^T: col=m)
                const int bb = m >> 9, t = m & 511;
                #pragma unroll
                for (int nf = 0; nf < 4; ++nf) {
                    const int nb = tn + wn * 64 + nf * 16 + quad * 4;
                    const int hh = (nb >> 6) & 7, dd = nb & 63;
                    short4v pk;
                    #pragma unroll
                    for (int r = 0; r < 4; ++r) pk[r] = f2bf_bits(acc[mf][nf][r]);
                    *(short4v*)&dst[((size_t)(bb * 8 + hh) * 512 + t) * 64 + dd] = pk;
                }
            }
        } else {
            bf16* dst = qkv + (size_t)2 * (8u << 20);
            #pragma unroll
            for (int mf = 0; mf < 4; ++mf) {
                const int mb = tm + wm * 64 + mf * 16 + quad * 4;   // token base
                const int bb = mb >> 9, t = mb & 511;
                #pragma unroll
                for (int nf = 0; nf < 4; ++nf) {
                    const int n = tn + wn * 64 + nf * 16 + l16;
                    const int hh = (n >> 6) & 7, dd = n & 63;
                    short4v pk;
                    #pragma unroll
                    for (int r = 0; r < 4; ++r) pk[r] = f2bf_bits(acc[mf][nf][r]);
                    *(short4v*)&dst[((size_t)(bb * 8 + hh) * 64 + dd) * 512 + t] = pk;
                }
            }
        }
    } else {
        #pragma unroll
        for (int mf = 0; mf < 4; ++mf) {
            const int m = tm + wm * 64 + mf * 16 + l16;             // C^T: col=m
            #pragma unroll
            for (int nf = 0; nf < 4; ++nf) {
                const int nb = tn + wn * 64 + nf * 16 + quad * 4;   // 4 consecutive n
                f32x4 a = acc[mf][nf];
                if (bias) a += *(const f32x4*)&bias[nb];
                if (RELU) {
                    #pragma unroll
                    for (int r = 0; r < 4; ++r) a[r] = fmaxf(a[r], 0.0f);
                }
                if (res)  a += *(const f32x4*)&res[(size_t)m * N + nb];
                if (OUT_BF16) {
                    short4v pk;
                    #pragma unroll
                    for (int r = 0; r < 4; ++r) pk[r] = f2bf_bits(a[r]);
                    *(short4v*)&((bf16*)outp)[(size_t)m * N + nb] = pk;
                } else {
                    *(f32x4*)&((float*)outp)[(size_t)m * N + nb] = a;
                }
            }
        }
    }
}

// ---------------- Flash attention: MFMA 16x16x32 bf16 (unchanged) ------------
__global__ __launch_bounds__(256) void attn_kernel(const bf16* __restrict__ q,
                                                   const bf16* __restrict__ kM,
                                                   const bf16* __restrict__ vT,
                                                   bf16* __restrict__ o)
{
    __shared__ __align__(16) bf16 Ks[64][72];
    __shared__ __align__(16) bf16 Vt[64][72];
    __shared__ __align__(16) bf16 Pw[4][16][72];

    const int qt   = gridDim.x - 1 - blockIdx.x;
    const int bh   = blockIdx.y;
    const int tid  = threadIdx.x;
    const int wave = tid >> 6, lane = tid & 63;
    const int l16  = lane & 15, quad = lane >> 4;
    const int qw   = qt * 64 + wave * 16;

    const float scale = 0.04419417382415922f;  // C^-0.5 (reference uses n_embd)
    bf16x8 qa[2];
    #pragma unroll
    for (int c = 0; c < 2; ++c) {
        const bf16* qp = q + ((size_t)bh * T_ + qw + l16) * 64 + c * 32 + quad * 8;
        bf16x8 t = *(const bf16x8*)qp;
        #pragma unroll
        for (int j = 0; j < 8; ++j) t[j] = f2bf_bits(bfbits2f(t[j]) * scale);
        qa[c] = t;
    }

    float m_i[4], l_i[4];
    f32x4 Of[4];
    #pragma unroll
    for (int r = 0; r < 4; ++r) { m_i[r] = -1e30f; l_i[r] = 0.0f; }
    #pragma unroll
    for (int f = 0; f < 4; ++f) Of[f] = (f32x4){0.f, 0.f, 0.f, 0.f};

    for (int kt = 0; kt <= qt; ++kt) {
        const int k0 = kt * 64;
        __syncthreads();
        #pragma unroll
        for (int c2 = 0; c2 < 2; ++c2) {
            const int ch = tid + c2 * 256;
            const int row = ch >> 3, e8 = (ch & 7) * 8;
            *(uint4*)&Ks[row][e8] = *(const uint4*)(kM + ((size_t)bh * T_ + k0 + row) * 64 + e8);
            *(uint4*)&Vt[row][e8] = *(const uint4*)(vT + ((size_t)bh * 64 + row) * T_ + k0 + e8);
        }
        __syncthreads();

        f32x4 Sf[4];
        #pragma unroll
        for (int kf = 0; kf < 4; ++kf) {
            bf16x8 b0 = *(const bf16x8*)&Ks[kf * 16 + l16][quad * 8];
            bf16x8 b1 = *(const bf16x8*)&Ks[kf * 16 + l16][32 + quad * 8];
            f32x4 z = (f32x4){0.f, 0.f, 0.f, 0.f};
            z = __builtin_amdgcn_mfma_f32_16x16x32_bf16(qa[0], b0, z, 0, 0, 0);
            z = __builtin_amdgcn_mfma_f32_16x16x32_bf16(qa[1], b1, z, 0, 0, 0);
            Sf[kf] = z;
        }

        if (kt == qt) {
            #pragma unroll
            for (int kf = 0; kf < 4; ++kf)
                #pragma unroll
                for (int r = 0; r < 4; ++r)
                    if (k0 + kf * 16 + l16 > qw + quad * 4 + r) Sf[kf][r] = -1e30f;
        }

        float mnew[4], alpha[4];
        #pragma unroll
        for (int r = 0; r < 4; ++r) {
            float v = fmaxf(fmaxf(Sf[0][r], Sf[1][r]), fmaxf(Sf[2][r], Sf[3][r]));
            v = fmaxf(v, __shfl_xor(v, 1, 64));
            v = fmaxf(v, __shfl_xor(v, 2, 64));
            v = fmaxf(v, __shfl_xor(v, 4, 64));
            v = fmaxf(v, __shfl_xor(v, 8, 64));
            mnew[r]  = fmaxf(m_i[r], v);
            alpha[r] = __expf(m_i[r] - mnew[r]);
            m_i[r]   = mnew[r];
        }

        float rs[4] = {0.f, 0.f, 0.f, 0.f};
        #pragma unroll
        for (int kf = 0; kf < 4; ++kf) {
            #pragma unroll
            for (int r = 0; r < 4; ++r) {
                float p = __expf(Sf[kf][r] - mnew[r]);
                rs[r] += p;
                Pw[wave][quad * 4 + r][kf * 16 + l16] = f2bf(p);
            }
        }
        #pragma unroll
        for (int r = 0; r < 4; ++r) {
            rs[r] += __shfl_xor(rs[r], 1, 64);
            rs[r] += __shfl_xor(rs[r], 2, 64);
            rs[r] += __shfl_xor(rs[r], 4, 64);
            rs[r] += __shfl_xor(rs[r], 8, 64);
            l_i[r] = l_i[r] * alpha[r] + rs[r];
        }
        #pragma unroll
        for (int f = 0; f < 4; ++f)
            #pragma unroll
            for (int r = 0; r < 4; ++r)
                Of[f][r] *= alpha[r];

        bf16x8 pa0 = *(const bf16x8*)&Pw[wave][l16][quad * 8];
        bf16x8 pa1 = *(const bf16x8*)&Pw[wave][l16][32 + quad * 8];
        #pragma unroll
        for (int f = 0; f < 4; ++f) {
            bf16x8 vb0 = *(const bf16x8*)&Vt[f * 16 + l16][quad * 8];
            bf16x8 vb1 = *(const bf16x8*)&Vt[f * 16 + l16][32 + quad * 8];
            Of[f] = __builtin_amdgcn_mfma_f32_16x16x32_bf16(pa0, vb0, Of[f], 0, 0, 0);
            Of[f] = __builtin_amdgcn_mfma_f32_16x16x32_bf16(pa1, vb1, Of[f], 0, 0, 0);
        }
    }

    const int b = bh >> 3, hh = bh & 7;
    #pragma unroll
    for (int r = 0; r < 4; ++r) {
        const float inv = 1.0f / l_i[r];
        const int t = qw + quad * 4 + r;
        #pragma unroll
        for (int f = 0; f < 4; ++f)
            o[((size_t)b * T_ + t) * C_ + hh * 64 + f * 16 + l16] = f2bf(Of[f][r] * inv);
    }
}

// -----------------------------------------------------------------------------
extern "C" void kernel_launch(void* const* d_in, const int* in_sizes, int n_in,
                              void* d_out, int out_size, void* d_ws, size_t ws_size,
                              hipStream_t stream)
{
    const float* x     = (const float*)d_in[0];
    const float* wq    = (const float*)d_in[1];
    const float* wk    = (const float*)d_in[2];
    const float* wv    = (const float*)d_in[3];
    const float* wproj = (const float*)d_in[4];
    const float* bproj = (const float*)d_in[5];
    const float* w1    = (const float*)d_in[6];
    const float* b1    = (const float*)d_in[7];
    const float* w2    = (const float*)d_in[8];
    const float* b2    = (const float*)d_in[9];
    const float* ln1g  = (const float*)d_in[10];
    const float* ln1b  = (const float*)d_in[11];
    const float* ln2g  = (const float*)d_in[12];
    const float* ln2b  = (const float*)d_in[13];

    // Workspace:
    //  [0,64M)    h,q,k,v (16 MB each; q/k/v contiguous for merged-QKV scatter)
    //             -> later mid (BT x 2048 bf16)
    //  [64,80M)   o (B,T,C bf16)
    //  [80,96M)   h2 (bf16)
    //  [96,102M)  Wt: qkvt[1536][512] | projt[512][512] | w1t[2048][512] | w2t[512][2048]
    //  x1 (f32) lives in d_out (same-thread RMW in final epilogue)
    char* ws = (char*)d_ws;
    bf16*  h    = (bf16*)(ws + 0);
    bf16*  q    = (bf16*)(ws + ((size_t)16 << 20));
    bf16*  k    = (bf16*)(ws + ((size_t)32 << 20));
    bf16*  v    = (bf16*)(ws + ((size_t)48 << 20));   // (B,H,D,T)
    bf16*  mid  = (bf16*)(ws + 0);
    bf16*  o    = (bf16*)(ws + ((size_t)64 << 20));
    bf16*  h2   = (bf16*)(ws + ((size_t)80 << 20));
    bf16*  wt   = (bf16*)(ws + ((size_t)96 << 20));
    bf16*  projt = wt + (size_t)1536 * 512;
    bf16*  w1t   = wt + (size_t)2048 * 512;
    bf16*  w2t   = wt + (size_t)4096 * 512;
    float* x1    = (float*)d_out;

    // 0. all weight transposes (f32 -> bf16, [N][K])
    transpose_all<<<768, 256, 0, stream>>>(wq, wk, wv, wproj, w1, w2, wt);

    // 1. h = LN1(x)
    ln_kernel<<<BT, 256, 0, stream>>>(x, ln1g, ln1b, h);

    // 2. q|k|v = h @ wqkv  (one N=1536 GEMM; v written (B,H,D,T))
    mfma_gemm<true,  false, true ><<<dim3(12, 128), 256, 0, stream>>>(h, wt, nullptr, nullptr, q, 1536, 512);

    // 3. o = flash-attn(q,k,v) -> (B,T,C)
    attn_kernel<<<dim3(8, B_ * H_), 256, 0, stream>>>(q, k, v, o);

    // 4. x1 = x + o @ w_proj + b_proj   (x1 = d_out, f32)
    mfma_gemm<false, false, false><<<dim3(4, 128), 256, 0, stream>>>(o, projt, bproj, x, x1, 512, 512);

    // 5. h2 = LN2(x1)
    ln_kernel<<<BT, 256, 0, stream>>>(x1, ln2g, ln2b, h2);

    // 6. mid = relu(h2 @ w1 + b1)
    mfma_gemm<false, true,  true ><<<dim3(16, 128), 256, 0, stream>>>(h2, w1t, b1, nullptr, mid, 2048, 512);

    // 7. out = x1 + mid @ w2 + b2   (in-place on d_out)
    mfma_gemm<false, false, false><<<dim3(4, 128), 256, 0, stream>>>(mid, w2t, b2, x1, (float*)d_out, 512, 2048);
}